// Round 14
// baseline (477.351 us; speedup 1.0000x reference)
//
#include <hip/hip_runtime.h>
#include <stdint.h>

// SChunkTransformerEncoderLayer: B=16, L=2048, C=512, HEADS=4, DK=128,
// CHUNK=16, nW=128, SHIFT=8. fp32 I/O, bf16 internal, fp32 accum.
// R14: R13 (best: 473us) + merged-window attention + bias fold:
//   - attn: ONE 1024-thread block per window (2048 blocks), all 4 heads.
//     Staging: wave li loads the full 1KB row segment of q/k/v (64 lanes x
//     16B, perfectly coalesced vs R13's 256B slivers x4 blocks). Row
//     stride 520 ushorts (1040B; 1040%128=16 -> same free 2-way bank
//     spread). Per-thread QK/softmax/PV identical with h folded into the
//     column offset; shfl groups (width 16) unchanged.
//   - bias_concat folded into wconv4 (grid 1030; blocks >=1024 copy bias).
//   GEMM/LN/wconvffn untouched from R13/R12.
//
// Workspace (256 MiB):
//   @0    : xn_s (32M)  -> att (32M)
//   @32M  : qkv (96M, stride 1536) -> x1@32M / W1t@64M / W2t@66M / xn2@96M
//   @128M : Wqkvt(1.5M)+Wot(0.5M)+bqkv(6K) -> h (128M)

typedef unsigned short bfu;

using bf16x8 = __attribute__((ext_vector_type(8))) __bf16;
using f32x4  = __attribute__((ext_vector_type(4))) float;

union U8 { uint4 v; unsigned short s[8]; };
union F4 { float4 v; float f[4]; };
union ABFrag { uint4 u; bf16x8 f; };

__device__ __forceinline__ float bf2f(unsigned short u) {
    union { uint32_t i; float f; } c; c.i = ((uint32_t)u) << 16; return c.f;
}
__device__ __forceinline__ unsigned short f2bf(float f) {
    union { float f; uint32_t i; } c; c.f = f;
    uint32_t x = c.i;
    return (unsigned short)((x + 0x7FFFu + ((x >> 16) & 1u)) >> 16);
}
__device__ __forceinline__ uint4 pack8(float4 a, float4 b) {
    U8 o;
    o.s[0] = f2bf(a.x); o.s[1] = f2bf(a.y); o.s[2] = f2bf(a.z); o.s[3] = f2bf(a.w);
    o.s[4] = f2bf(b.x); o.s[5] = f2bf(b.y); o.s[6] = f2bf(b.z); o.s[7] = f2bf(b.w);
    return o.v;
}

#define GLDS16(gp, lp)                                                        \
    __builtin_amdgcn_global_load_lds(                                         \
        (__attribute__((address_space(1))) void*)(gp),                        \
        (__attribute__((address_space(3))) void*)(lp), 16, 0, 0)

// ---- weight packing: 4x 512x512 transposes (Wq,Wk,Wv -> Wqkvt; Wo -> Wot)
// flat grid 1030: blocks 0..1023 transpose (z = b>>8 selects matrix,
// r = b&255 -> 16x16 32-tile grid); blocks 1024..1029 copy the qkv bias.

__global__ __launch_bounds__(256) void wconv4_kernel(
    const float* __restrict__ Wq, const float* __restrict__ Wk,
    const float* __restrict__ Wv, const float* __restrict__ Wo,
    bfu* __restrict__ Wqkvt, bfu* __restrict__ Wot,
    const float* __restrict__ bq, const float* __restrict__ bk,
    const float* __restrict__ bv, float* __restrict__ bqkv)
{
    __shared__ float t[32][33];
    const int b = blockIdx.x;
    if (b >= 1024) {           // bias concat: 6 blocks x 256 = 1536 elems
        const int i = (b - 1024) * 256 + threadIdx.x;
        const float* src = (i < 512) ? bq : (i < 1024) ? bk : bv;
        bqkv[i] = src[i & 511];
        return;
    }
    const int z = b >> 8;
    const int r = b & 255;
    const float* W = (z == 0) ? Wq : (z == 1) ? Wk : (z == 2) ? Wv : Wo;
    bfu* Wt = (z < 3) ? (Wqkvt + (size_t)z * 512 * 512) : Wot;
    const int bn = (r & 15) << 5;
    const int bk2 = (r >> 4) << 5;
    const int tx = threadIdx.x & 31, ty = threadIdx.x >> 5;
#pragma unroll
    for (int i = 0; i < 32; i += 8)
        t[ty + i][tx] = W[(size_t)(bk2 + ty + i) * 512 + bn + tx];
    __syncthreads();
#pragma unroll
    for (int i = 0; i < 32; i += 8)
        Wt[(size_t)(bn + ty + i) * 512 + bk2 + tx] = f2bf(t[tx][ty + i]);
}

// ---- FFN weight packing: W1 (512x2048 -> W1t[2048][512]) and
// W2 (2048x512 -> W2t[512][2048]) in one flat launch (1024 + 1024 blocks).

__global__ __launch_bounds__(256) void wconvffn_kernel(
    const float* __restrict__ W1, const float* __restrict__ W2,
    bfu* __restrict__ W1t, bfu* __restrict__ W2t)
{
    __shared__ float t[32][33];
    const int b = blockIdx.x;
    const int tx = threadIdx.x & 31, ty = threadIdx.x >> 5;
    if (b < 1024) {            // W1: K=512, N=2048 -> 64 x 16 tiles
        const int bn = (b & 63) << 5;
        const int bk = (b >> 6) << 5;
#pragma unroll
        for (int i = 0; i < 32; i += 8)
            t[ty + i][tx] = W1[(size_t)(bk + ty + i) * 2048 + bn + tx];
        __syncthreads();
#pragma unroll
        for (int i = 0; i < 32; i += 8)
            W1t[(size_t)(bn + ty + i) * 512 + bk + tx] = f2bf(t[tx][ty + i]);
    } else {                   // W2: K=2048, N=512 -> 16 x 64 tiles
        const int r = b - 1024;
        const int bn = (r & 15) << 5;
        const int bk = (r >> 4) << 5;
#pragma unroll
        for (int i = 0; i < 32; i += 8)
            t[ty + i][tx] = W2[(size_t)(bk + ty + i) * 512 + bn + tx];
        __syncthreads();
#pragma unroll
        for (int i = 0; i < 32; i += 8)
            W2t[(size_t)(bn + ty + i) * 2048 + bk + tx] = f2bf(t[tx][ty + i]);
    }
}

// ---------------- LayerNorm kernels (one wave per row, 4 rows/block) -------

__global__ __launch_bounds__(256) void ln1_shift_kernel(
    const float* __restrict__ x, const float* __restrict__ g,
    const float* __restrict__ be, bfu* __restrict__ out)
{
    const int ms = (blockIdx.x << 2) + (threadIdx.x >> 6);
    const int b = ms >> 11;
    const int ls = ms & 2047;
    const int l = (ls + 8) & 2047;
    const int c0 = (threadIdx.x & 63) << 3;
    const float* xp = x + ((((size_t)(b << 11)) + l) << 9) + c0;
    F4 f0, f1; f0.v = *(const float4*)xp; f1.v = *(const float4*)(xp + 4);
    float vv[8]; float s = 0.f, sq = 0.f;
#pragma unroll
    for (int j = 0; j < 4; ++j) { vv[j] = f0.f[j]; vv[4 + j] = f1.f[j]; }
#pragma unroll
    for (int j = 0; j < 8; ++j) { s += vv[j]; sq += vv[j] * vv[j]; }
#pragma unroll
    for (int o = 32; o > 0; o >>= 1) { s += __shfl_xor(s, o); sq += __shfl_xor(sq, o); }
    const float mean = s * (1.f / 512.f);
    float var = sq * (1.f / 512.f) - mean * mean;
    var = fmaxf(var, 0.f);
    const float rstd = rsqrtf(var + 1e-12f);
    F4 g0, g1v, b0, b1;
    g0.v = *(const float4*)(g + c0);  g1v.v = *(const float4*)(g + c0 + 4);
    b0.v = *(const float4*)(be + c0); b1.v = *(const float4*)(be + c0 + 4);
    U8 o8;
#pragma unroll
    for (int j = 0; j < 4; ++j) {
        o8.s[j]     = f2bf((vv[j]     - mean) * rstd * g0.f[j]  + b0.f[j]);
        o8.s[4 + j] = f2bf((vv[4 + j] - mean) * rstd * g1v.f[j] + b1.f[j]);
    }
    *(uint4*)(out + (((size_t)ms) << 9) + c0) = o8.v;
}

__global__ __launch_bounds__(256) void ln2_kernel(
    const bfu* __restrict__ x1, const float* __restrict__ g,
    const float* __restrict__ be, bfu* __restrict__ out)
{
    const int ms = (blockIdx.x << 2) + (threadIdx.x >> 6);
    const int c0 = (threadIdx.x & 63) << 3;
    U8 u; u.v = *(const uint4*)(x1 + (((size_t)ms) << 9) + c0);
    float vv[8]; float s = 0.f, sq = 0.f;
#pragma unroll
    for (int j = 0; j < 8; ++j) { float f = bf2f(u.s[j]); vv[j] = f; s += f; sq += f * f; }
#pragma unroll
    for (int o = 32; o > 0; o >>= 1) { s += __shfl_xor(s, o); sq += __shfl_xor(sq, o); }
    const float mean = s * (1.f / 512.f);
    float var = sq * (1.f / 512.f) - mean * mean;
    var = fmaxf(var, 0.f);
    const float rstd = rsqrtf(var + 1e-12f);
    F4 g0, g1v, b0, b1;
    g0.v = *(const float4*)(g + c0);  g1v.v = *(const float4*)(g + c0 + 4);
    b0.v = *(const float4*)(be + c0); b1.v = *(const float4*)(be + c0 + 4);
    U8 o8;
#pragma unroll
    for (int j = 0; j < 4; ++j) {
        o8.s[j]     = f2bf((vv[j]     - mean) * rstd * g0.f[j]  + b0.f[j]);
        o8.s[4 + j] = f2bf((vv[4 + j] - mean) * rstd * g1v.f[j] + b1.f[j]);
    }
    *(uint4*)(out + (((size_t)ms) << 9) + c0) = o8.v;
}

// ---------------- MFMA GEMM: 256x256 tile, 4 single-barrier phases --------
// (R7/R9/R12 structure, verified ~99us big-GEMM, no spill.)
// 8 waves (2Mx4N), wave tile 128x64 = acc[8][4] of 16x16x32 frags, BK=64.
// LDS 128 KiB: buf d at d*64KB; A [256][64]bf16 at +0, B at +32KB.
// Swizzle: LDS row r, 16B-slot s holds global k-chunk (s ^ (r&7)); stage
// linear dest + inverse-swizzled global src; ds_read col ^ ((l15&7)<<4).
// Per K-tile t (buf D=t&1; stage targets t+2 -> same buf D):
//  P0: [bar] rd A(MH0)+B(NH0)          ; MFMA Q(0,0)
//  P1: [bar] rd B(NH1)                 ; MFMA Q(0,1)
//  P2: [bar] rd A(MH1); STAGE B4       ; MFMA Q(1,0)
//  P3: [bar] STAGE A4                  ; MFMA Q(1,1); vmcnt(8)
// EPI 0: Ob=bf16(Y)  1: Ob=bf16(relu Y)
// EPI 2: Ob[unshifted] = bf16(xres + Y*mp)   3: Ofl = bf2f(prevb) + Y

template<int EPI>
__global__ __launch_bounds__(512, 2) void mgemm(
    const bfu* __restrict__ X, const bfu* __restrict__ Wt,
    const float* __restrict__ bias,
    bfu* Ob, float* Ofl,
    const float* __restrict__ xres, const bfu* __restrict__ prevb,
    const float* __restrict__ maskpad,
    int M, int N, int K)
{
    __shared__ __align__(16) char smem[131072];
    bfu* smb = (bfu*)smem;
    const char* smc = (const char*)smem;
    float* epi = (float*)smem;

    const int t = threadIdx.x;
    const int lane = t & 63;
    const int w = t >> 6;              // 0..7
    const int wm = w >> 2, wn = w & 3; // 2 x 4 wave grid
    const int q = lane >> 4, l15 = lane & 15;

    // XCD-aware bijective block swizzle (nwg % 8 == 0 for all our grids)
    const int gx = gridDim.x;
    const int nwg = gx * gridDim.y;
    int wid = blockIdx.y * gx + blockIdx.x;
    wid = ((wid & 7) * (nwg >> 3)) + (wid >> 3);
    const int row0 = (wid / gx) << 8;
    const int col0 = (wid % gx) << 8;

    // staging: thread covers row (stmt*64 + w*8 + lane/8),
    // global chunk (lane&7)^((lane>>3)&7); LDS dest linear lane*16B.
    const int srow = (w << 3) + (lane >> 3);
    const int scol = (((lane & 7) ^ ((lane >> 3) & 7)) << 3);
    const bfu* gA = X  + (size_t)(row0 + srow) * K + scol;
    const bfu* gB = Wt + (size_t)(col0 + srow) * K + scol;
    bfu* lsA0 = smb + (w << 9) + (lane << 3);
    bfu* lsB0 = lsA0 + 16384;
    bfu* lsA1 = lsA0 + 32768;
    bfu* lsB1 = lsA0 + 49152;

    // frag read bases (bytes)
    const int arow = ((wm << 7) + l15) << 7;   // (wm*128+l15)*128
    const int brow = ((wn << 6) + l15) << 7;   // (wn*64 +l15)*128
    const int qb   = q << 4;
    const int swz  = (l15 & 7) << 4;

    // bias preloaded into accumulators
    f32x4 acc[8][4];
    float bv[4];
#pragma unroll
    for (int j = 0; j < 4; ++j) bv[j] = bias[col0 + (wn << 6) + (j << 4) + l15];
#pragma unroll
    for (int i = 0; i < 8; ++i)
#pragma unroll
        for (int j = 0; j < 4; ++j) {
            acc[i][j][0] = bv[j]; acc[i][j][1] = bv[j];
            acc[i][j][2] = bv[j]; acc[i][j][3] = bv[j];
        }

    ABFrag a[4][2];        // current A half (single-buffered - fits budget)
    ABFrag bb[2][2][2];    // full B tile: [NH][nf][kk], register-resident

#define SB_   __builtin_amdgcn_s_barrier()
#define VM8_  asm volatile("s_waitcnt vmcnt(8)" ::: "memory")
#define VM0_  asm volatile("s_waitcnt vmcnt(0)" ::: "memory")
#define VMNOP_ do {} while (0)

#define LDA_(D, MH)                                                           \
    _Pragma("unroll") for (int mf = 0; mf < 4; ++mf)                          \
    _Pragma("unroll") for (int kk = 0; kk < 2; ++kk)                          \
        a[mf][kk].u = *(const uint4*)(smc + (D)*65536 + arow + (MH)*8192 +    \
                                      mf*2048 + (((kk << 6) + qb) ^ swz));
#define LDB_(D, NH)                                                           \
    _Pragma("unroll") for (int nf = 0; nf < 2; ++nf)                          \
    _Pragma("unroll") for (int kk = 0; kk < 2; ++kk)                          \
        bb[NH][nf][kk].u = *(const uint4*)(smc + (D)*65536 + 32768 + brow +   \
                                      (NH)*4096 + nf*2048 +                   \
                                      (((kk << 6) + qb) ^ swz));
#define MFMAQ_(MH, NH)                                                        \
    __builtin_amdgcn_s_setprio(1);                                            \
    _Pragma("unroll") for (int mf = 0; mf < 4; ++mf)                          \
    _Pragma("unroll") for (int nf = 0; nf < 2; ++nf) {                        \
        acc[(MH)*4+mf][(NH)*2+nf] = __builtin_amdgcn_mfma_f32_16x16x32_bf16(  \
            a[mf][0].f, bb[NH][nf][0].f, acc[(MH)*4+mf][(NH)*2+nf], 0, 0, 0); \
        acc[(MH)*4+mf][(NH)*2+nf] = __builtin_amdgcn_mfma_f32_16x16x32_bf16(  \
            a[mf][1].f, bb[NH][nf][1].f, acc[(MH)*4+mf][(NH)*2+nf], 0, 0, 0);}\
    __builtin_amdgcn_s_setprio(0);
#define STGA4_(D, GA2) do {                                                   \
    GLDS16((GA2), lsA##D);                                                    \
    GLDS16((GA2) + (size_t)64  * K, lsA##D + 4096);                           \
    GLDS16((GA2) + (size_t)128 * K, lsA##D + 8192);                           \
    GLDS16((GA2) + (size_t)192 * K, lsA##D + 12288); } while (0)
#define STGB4_(D, GB2) do {                                                   \
    GLDS16((GB2), lsB##D);                                                    \
    GLDS16((GB2) + (size_t)64  * K, lsB##D + 4096);                           \
    GLDS16((GB2) + (size_t)128 * K, lsB##D + 8192);                           \
    GLDS16((GB2) + (size_t)192 * K, lsB##D + 12288); } while (0)
// single-barrier phases; tile t in buf D; stages t+2 -> same buf D
#define TILE_(D, DOSTG, VMW) do {                                             \
    SB_;                                                                      \
    LDA_(D, 0); LDB_(D, 0);                                                   \
    MFMAQ_(0, 0);                                                             \
    SB_;                                                                      \
    LDB_(D, 1);                                                               \
    MFMAQ_(0, 1);                                                             \
    SB_;                                                                      \
    LDA_(D, 1);                                                               \
    if (DOSTG) STGB4_(D, gB2);                                                \
    MFMAQ_(1, 0);                                                             \
    SB_;                                                                      \
    if (DOSTG) STGA4_(D, gA2);                                                \
    MFMAQ_(1, 1);                                                             \
    VMW;                                                                      \
} while (0)

    const int nT = K >> 6;   // K in {512, 2048} -> nT in {8, 32}, even

    // prologue: stage tiles 0 (buf0) and 1 (buf1); per-wave wait for tile0
    // (cross-wave visibility comes from the loop's first P0 barrier)
    STGA4_(0, gA); STGB4_(0, gB);
    {
        const bfu* ga1 = gA + 64; const bfu* gb1 = gB + 64;
        STGA4_(1, ga1); STGB4_(1, gb1);
    }
    VM8_;

    const bfu* gA2 = gA + 128;   // tile 2
    const bfu* gB2 = gB + 128;
#pragma unroll 1
    for (int tt = 0; tt < nT - 2; tt += 2) {
        TILE_(0, true, VM8_);
        gA2 += 64; gB2 += 64;
        TILE_(1, true, VM8_);
        gA2 += 64; gB2 += 64;
    }
    TILE_(0, false, VM0_);       // tile nT-2: drain remaining DMA
    TILE_(1, false, VMNOP_);     // tile nT-1

#undef LDA_
#undef LDB_
#undef MFMAQ_
#undef STGA4_
#undef STGB4_
#undef TILE_

    SB_;   // all waves done with LDS buffers (and DMA drained) before alias

    // epilogue: per wave stage 16x64 fp32 in LDS, store coalesced
    float* epw = epi + w * 1088;                    // [16][68]
    const int c8 = (lane & 7) << 3;
    const int r8 = lane >> 3;
    const int colg = col0 + (wn << 6) + c8;
#pragma unroll
    for (int i = 0; i < 8; ++i) {
#pragma unroll
        for (int j = 0; j < 4; ++j)
#pragma unroll
            for (int r = 0; r < 4; ++r) {
                float y = acc[i][j][r];
                if (EPI == 1) y = fmaxf(y, 0.f);
                epw[((q << 2) + r) * 68 + (j << 4) + l15] = y;
            }
        __builtin_amdgcn_wave_barrier();
#pragma unroll
        for (int h = 0; h < 2; ++h) {
            const int rr = r8 + (h << 3);
            F4 f0, f1;
            f0.v = *(const float4*)&epw[rr * 68 + c8];
            f1.v = *(const float4*)&epw[rr * 68 + c8 + 4];
            const int row_out = row0 + (wm << 7) + (i << 4) + rr;
            if (EPI == 0 || EPI == 1) {
                *(uint4*)(Ob + (size_t)row_out * N + colg) = pack8(f0.v, f1.v);
            } else if (EPI == 2) {
                const int bb2 = row_out >> 11;
                const int ls = row_out & 2047;
                const int l = (ls + 8) & 2047;      // reverse shift
                const float mp = maskpad[(bb2 << 11) + l];
                const size_t dst = ((size_t)(bb2 << 11) + l) * (size_t)N + colg;
                F4 x0, x1v;
                x0.v = *(const float4*)(xres + dst);
                x1v.v = *(const float4*)(xres + dst + 4);
                F4 o0, o1;
#pragma unroll
                for (int jj = 0; jj < 4; ++jj) {
                    o0.f[jj] = x0.f[jj]  + f0.f[jj] * mp;
                    o1.f[jj] = x1v.f[jj] + f1.f[jj] * mp;
                }
                *(uint4*)(Ob + dst) = pack8(o0.v, o1.v);
            } else { // EPI 3
                const size_t dst = (size_t)row_out * N + colg;
                U8 pb; pb.v = *(const uint4*)(prevb + dst);
                F4 o0, o1;
#pragma unroll
                for (int jj = 0; jj < 4; ++jj) {
                    o0.f[jj] = bf2f(pb.s[jj])     + f0.f[jj];
                    o1.f[jj] = bf2f(pb.s[4 + jj]) + f1.f[jj];
                }
                *(float4*)(Ofl + dst) = o0.v;
                *(float4*)(Ofl + dst + 4) = o1.v;
            }
        }
        __builtin_amdgcn_wave_barrier();
    }
}

// ---------------- Windowed attention: one block per window, 4 heads ------
// 1024 threads (16 waves). bf16 LDS, row stride 520 ushorts (1040B:
// 16B-aligned; 1040%128=16 -> free 2-way bank spread, same as R13).
// Staging: wave li loads the FULL 1KB row segment of q/k/v (64 lanes x 16B,
// perfectly coalesced). Thread (h,qi,ki) = (t>>8, (t>>4)&15, t&15); h is
// wave-uniform (w>>2), qi fixed within each 16-lane group -> shfl width 16
// softmax unchanged. PV: thread (h, li=qi, dc=ki) with col = h*128+dc*8.

__global__ __launch_bounds__(1024) void attn_kernel(
    const bfu* __restrict__ qkv, const float* __restrict__ mpad,
    bfu* __restrict__ out)
{
    __shared__ bfu qs[16][520];
    __shared__ bfu ks[16][520];
    __shared__ bfu vs[16][520];
    __shared__ float ps[4][16][17];
    const int t = threadIdx.x;
    const int wg = blockIdx.x;           // window 0..2047
    const int b = wg >> 7;
    const int w = wg & 127;
    {
        const int row = t >> 6;          // one wave per row
        const int c8 = (t & 63) << 3;    // 64 lanes x 8 bf16 = full 512
        const size_t base = (((size_t)wg << 4) + row) * 1536 + c8;
        *(uint4*)&qs[row][c8] = *(const uint4*)(qkv + base);
        *(uint4*)&ks[row][c8] = *(const uint4*)(qkv + base + 512);
        *(uint4*)&vs[row][c8] = *(const uint4*)(qkv + base + 1024);
    }
    __syncthreads();
    const int h  = t >> 8;
    const int qi = (t >> 4) & 15;
    const int ki = t & 15;
    const int hb = h << 7;
    float s = 0.f;
#pragma unroll
    for (int d = 0; d < 128; d += 8) {
        U8 qv, kv;
        qv.v = *(const uint4*)&qs[qi][hb + d];
        kv.v = *(const uint4*)&ks[ki][hb + d];
#pragma unroll
        for (int j = 0; j < 8; ++j)
            s += bf2f(qv.s[j]) * bf2f(kv.s[j]);
    }
    s *= 0.088388347648318447f;
    const bool lastw = (w == 127);
    if (lastw ? (qi >= 8 && ki >= 8) : (qi < 7 && ki >= 8)) s -= 100.f;
    const int lkey = ((w << 4) + ki + 8) & 2047;
    const bool valid = mpad[(b << 11) + lkey] > 0.f;
    if (!valid) s = -1e30f;
    float mx = s;
#pragma unroll
    for (int o = 8; o > 0; o >>= 1) mx = fmaxf(mx, __shfl_xor(mx, o, 16));
    float e = __expf(s - mx);
    float sum = e;
#pragma unroll
    for (int o = 8; o > 0; o >>= 1) sum += __shfl_xor(sum, o, 16);
    float p = e / sum;
    if (!valid) p = 0.f;
    ps[h][qi][ki] = p;
    __syncthreads();
    // PV: li = qi, d-chunk = ki
    const int d0 = hb + (ki << 3);
    float o_[8];
#pragma unroll
    for (int j = 0; j < 8; ++j) o_[j] = 0.f;
#pragma unroll
    for (int kk = 0; kk < 16; ++kk) {
        const float pw = ps[h][qi][kk];
        U8 vv8;
        vv8.v = *(const uint4*)&vs[kk][d0];
#pragma unroll
        for (int j = 0; j < 8; ++j)
            o_[j] += pw * bf2f(vv8.s[j]);
    }
    U8 o8;
#pragma unroll
    for (int j = 0; j < 8; ++j) o8.s[j] = f2bf(o_[j]);
    *(uint4*)(out + (((size_t)wg << 4) + qi) * 512 + d0) = o8.v;
}

// ---------------- Launch ----------------

extern "C" void kernel_launch(void* const* d_in, const int* in_sizes, int n_in,
                              void* d_out, int out_size, void* d_ws, size_t ws_size,
                              hipStream_t stream)
{
    const float* x    = (const float*)d_in[0];
    const float* mpad = (const float*)d_in[3];
    const float* Wq = (const float*)d_in[4];  const float* bq = (const float*)d_in[5];
    const float* Wk = (const float*)d_in[6];  const float* bk = (const float*)d_in[7];
    const float* Wv = (const float*)d_in[8];  const float* bv = (const float*)d_in[9];
    const float* Wo = (const float*)d_in[10]; const float* bo = (const float*)d_in[11];
    const float* g1 = (const float*)d_in[12]; const float* be1 = (const float*)d_in[13];
    const float* g2 = (const float*)d_in[14]; const float* be2 = (const float*)d_in[15];
    const float* W1 = (const float*)d_in[16]; const float* bf1 = (const float*)d_in[17];
    const float* W2 = (const float*)d_in[18]; const float* bf2 = (const float*)d_in[19];
    float* out = (float*)d_out;

    char* p = (char*)d_ws;
    const size_t MB = (size_t)1 << 20;
    bfu* xn_s = (bfu*)p;                     // @0; later att
    bfu* att  = xn_s;
    bfu* qkv  = (bfu*)(p + 32 * MB);         // 96 MiB, stride 1536
    bfu* x1   = qkv;                         // @32M after attn
    bfu* W1t  = (bfu*)(p + 64 * MB);         // 2 MiB
    bfu* W2t  = (bfu*)(p + 66 * MB);         // 2 MiB
    bfu* xn2  = (bfu*)(p + 96 * MB);         // 32 MiB
    bfu* hreg = (bfu*)(p + 128 * MB);        // 128 MiB; head holds Wqkvt/Wot early
    bfu* Wqkvt = hreg;                       // 1.5 MiB
    bfu* Wot   = hreg + 1536 * 512;          // 0.5 MiB
    float* bqkv = (float*)(hreg + 2048 * 512);  // 6 KiB

    const int M = 32768;
    dim3 blk(256);
    dim3 blk5(512);

    // pack weights + qkv bias (blocks 1024..1029)
    wconv4_kernel<<<dim3(1030), blk, 0, stream>>>(Wq, Wk, Wv, Wo, Wqkvt, Wot,
                                                  bq, bk, bv, bqkv);

    ln1_shift_kernel<<<8192, blk, 0, stream>>>(x, g1, be1, xn_s);

    // fused QKV: [32768 x 1536], K=512
    mgemm<0><<<dim3(6, 128), blk5, 0, stream>>>(xn_s, Wqkvt, bqkv, qkv, nullptr, nullptr, nullptr, nullptr, M, 1536, 512);

    attn_kernel<<<dim3(2048), dim3(1024), 0, stream>>>(qkv, mpad, att);

    // FFN weights into dead qkv region
    wconvffn_kernel<<<dim3(2048), blk, 0, stream>>>(W1, W2, W1t, W2t);

    mgemm<2><<<dim3(2, 128), blk5, 0, stream>>>(att, Wot, bo, x1, nullptr, x, nullptr, mpad, M, 512, 512);

    ln2_kernel<<<8192, blk, 0, stream>>>(x1, g2, be2, xn2);

    mgemm<1><<<dim3(8, 128), blk5, 0, stream>>>(xn2, W1t, bf1, hreg, nullptr, nullptr, nullptr, nullptr, M, 2048, 512);
    mgemm<3><<<dim3(2, 128), blk5, 0, stream>>>(hreg, W2t, bf2, nullptr, out, nullptr, x1, nullptr, M, 512, 2048);
}